// Round 12
// baseline (673.306 us; speedup 1.0000x reference)
//
#include <hip/hip_runtime.h>
#include <stdint.h>

typedef unsigned short u16;
typedef __attribute__((ext_vector_type(8))) short bf16x8;
typedef __attribute__((ext_vector_type(8))) u16 u16x8;
typedef __attribute__((ext_vector_type(4))) float f32x4;

static __device__ __forceinline__ u16 f2b(float f) {
  uint32_t u = __builtin_bit_cast(uint32_t, f);
  u += 0x7fffu + ((u >> 16) & 1u);
  return (u16)(u >> 16);
}
static __device__ __forceinline__ float b2f(u16 h) {
  uint32_t u = ((uint32_t)h) << 16;
  return __builtin_bit_cast(float, u);
}

#define GLDS16(gsrc, ldst)                                                        \
  __builtin_amdgcn_global_load_lds(                                               \
      (const __attribute__((address_space(1))) void*)(gsrc),                      \
      (__attribute__((address_space(3))) void*)(ldst), 16, 0, 0)

// ---------------- all setup work in ONE kernel (validated R9) ----------------
__global__ __launch_bounds__(256) void setup_kernel(
    const float* __restrict__ ipw, u16* __restrict__ ipwb,
    const float* __restrict__ xpw, u16* __restrict__ xpwb,
    const float* __restrict__ opw, u16* __restrict__ opwb,
    const float* __restrict__ sow1, u16* __restrict__ sow1b,
    const float* __restrict__ sow2, u16* __restrict__ sow2b,
    const float* __restrict__ row1, u16* __restrict__ row1b,
    float* __restrict__ PEt,
    const float* __restrict__ dpw, float* __restrict__ dpwT,
    const float* __restrict__ cw, float* __restrict__ cwT) {
  int i = blockIdx.x * 256 + threadIdx.x;
  if (i < 4194304) { ipwb[i] = f2b(ipw[i]); return; } i -= 4194304;
  if (i < 262144)  { xpwb[i] = f2b(xpw[i]); return; } i -= 262144;
  if (i < 2097152) { opwb[i] = f2b(opw[i]); return; } i -= 2097152;
  if (i < 131072)  { sow1b[i] = f2b(sow1[i]); return; } i -= 131072;
  if (i < 32768)   { sow2b[i] = f2b(sow2[i]); return; } i -= 32768;
  if (i < 131072)  { row1b[i] = f2b(row1[i]); return; } i -= 131072;
  if (i < 524288) {  // PE: i = l*512 + dd
    int dd = i & 511, l = i >> 9;
    const float cc = -9.210340371976184f / 512.f;
    float div = expf((float)(2 * (dd >> 1)) * cc);
    PEt[i] = (dd & 1) ? cosf((float)l * div) : sinf((float)l * div);
    return;
  } i -= 524288;
  if (i < 131072) {  // dpwT[l][j][dd] = dpw[l][dd][j]
    int l = i >> 15, r = i & 32767, j = r >> 10, dd = r & 1023;
    dpwT[i] = dpw[(size_t)l * 32768 + (size_t)dd * 32 + j];
    return;
  } i -= 131072;
  if (i < 16384) {   // cwT[l][k][dd] = cw[l][dd][k]
    int l = i >> 12, r = i & 4095, k = r >> 10, dd = r & 1023;
    cwT[i] = cw[(size_t)l * 4096 + (size_t)dd * 4 + k];
  }
}

// ---------------- embedding + PE + LayerNorm (16 tokens/block) ----------------
__global__ __launch_bounds__(256) void embed_ln2(
    const float* __restrict__ x, const float* __restrict__ rtg,
    const float* __restrict__ Wse, const float* __restrict__ bse,
    const float* __restrict__ Wre, const float* __restrict__ bre,
    const float* __restrict__ lnw, const float* __restrict__ lnb,
    const float* __restrict__ PEt, float* __restrict__ h) {
  const int tid = threadIdx.x;
  const int tok0 = blockIdx.x * 16;
  const int l0 = tok0 & 1023;
  __shared__ float xs[16][128];
  __shared__ float rt[16];
  __shared__ float sw[16][2][4];
  for (int i = tid; i < 16 * 128; i += 256) ((float*)xs)[i] = x[(size_t)tok0 * 128 + i];
  if (tid < 16) rt[tid] = rtg[tok0 + tid];
  __syncthreads();
  const int d = tid;
  float acc[16];
#pragma unroll
  for (int tt = 0; tt < 16; ++tt) acc[tt] = 0.f;
  const float* wrow = Wse + (size_t)d * 128;
  for (int k0 = 0; k0 < 128; k0 += 8) {
    float4 wa = *(const float4*)(wrow + k0);
    float4 wb = *(const float4*)(wrow + k0 + 4);
#pragma unroll
    for (int tt = 0; tt < 16; ++tt) {
      const float* xr = &xs[tt][k0];
      acc[tt] += xr[0] * wa.x + xr[1] * wa.y + xr[2] * wa.z + xr[3] * wa.w +
                 xr[4] * wb.x + xr[5] * wb.y + xr[6] * wb.z + xr[7] * wb.w;
    }
  }
  const float seb = bse[d], reW = Wre[d], reB = bre[d];
  const int lane = tid & 63, wv = tid >> 6;
  float h1a[16];
#pragma unroll
  for (int tt = 0; tt < 16; ++tt) {
    float h0 = acc[tt] + seb + PEt[(size_t)(l0 + tt) * 512 + d];
    float h1 = reB + rt[tt] * reW + PEt[(size_t)(l0 + tt) * 512 + 256 + d];
    acc[tt] = h0;
    h1a[tt] = h1;
    float s = h0 + h1, q = h0 * h0 + h1 * h1;
#pragma unroll
    for (int o = 32; o; o >>= 1) { s += __shfl_xor(s, o); q += __shfl_xor(q, o); }
    if (lane == 0) { sw[tt][0][wv] = s; sw[tt][1][wv] = q; }
  }
  __syncthreads();
#pragma unroll
  for (int tt = 0; tt < 16; ++tt) {
    float S = sw[tt][0][0] + sw[tt][0][1] + sw[tt][0][2] + sw[tt][0][3];
    float Q = sw[tt][1][0] + sw[tt][1][1] + sw[tt][1][2] + sw[tt][1][3];
    float mean = S * (1.f / 512.f);
    float var = Q * (1.f / 512.f) - mean * mean;
    float rstd = rsqrtf(var + 1e-5f);
    size_t base = (size_t)(tok0 + tt) * 512;
    h[base + d]       = (acc[tt] - mean) * rstd * lnw[d] + lnb[d];
    h[base + 256 + d] = (h1a[tt] - mean) * rstd * lnw[256 + d] + lnb[256 + d];
  }
}

// ---------------- residual add + RMSNorm -> bf16 ----------------
__global__ __launch_bounds__(256) void resid_rms_kernel(
    const float* __restrict__ hin, float* __restrict__ residual,
    const float* __restrict__ w, u16* __restrict__ outb, int first) {
  const int tok = blockIdx.x;
  const int t = threadIdx.x;
  __shared__ float rq[4];
  size_t base = (size_t)tok * 512;
  float v0 = hin[base + t], v1 = hin[base + t + 256];
  if (!first) { v0 += residual[base + t]; v1 += residual[base + t + 256]; }
  residual[base + t] = v0;
  residual[base + t + 256] = v1;
  float q = v0 * v0 + v1 * v1;
#pragma unroll
  for (int o = 32; o; o >>= 1) q += __shfl_xor(q, o);
  if ((t & 63) == 0) rq[t >> 6] = q;
  __syncthreads();
  float Q = rq[0] + rq[1] + rq[2] + rq[3];
  float scale = rsqrtf(Q * (1.f / 512.f) + 1e-5f);
  outb[base + t]       = f2b(v0 * scale * w[t]);
  outb[base + t + 256] = f2b(v1 * scale * w[t + 256]);
}

// ---------------- MFMA GEMM: C[M,N] = A[M,K] * Bw[N,K]^T ----------------
// As = A row stride. EPI: 0=f32, 1=bf16, 2=bias+relu->bf16, 3=bias->f32,
// 4=dual-bias+relu->bf16 (bias[col<256], bias2[col-256])
template <int BM, int BN, int WM, int WN, int EPI>
__global__ __launch_bounds__(256) void gemm_bt(
    const u16* __restrict__ A, const u16* __restrict__ Bw,
    float* __restrict__ Cf, u16* __restrict__ Cb,
    const float* __restrict__ bias, const float* __restrict__ bias2,
    int M, int N, int K, int As) {
  constexpr int MF = BM / (WM * 16);
  constexpr int NF = BN / (WN * 16);
  constexpr int NCA = (BM * 4) / 256;
  constexpr int NCB = (BN * 4) / 256;
  __shared__ __align__(16) u16 lA[BM * 32];
  __shared__ __align__(16) u16 lB[BN * 32];
  const int tid = threadIdx.x;
  const int lane = tid & 63;
  const int wv = tid >> 6;
  const int wr = wv / WN, wc = wv % WN;
  const int m0 = blockIdx.x * BM, n0 = blockIdx.y * BN;
  const int kchunk = K / gridDim.z;
  const int kb = blockIdx.z * kchunk;

  f32x4 acc[MF][NF];
#pragma unroll
  for (int i = 0; i < MF; ++i)
#pragma unroll
    for (int j = 0; j < NF; ++j) acc[i][j] = (f32x4){0.f, 0.f, 0.f, 0.f};

  const int srow = tid >> 2, sck = tid & 3;
  const u16* Ag = A + (size_t)(m0 + srow) * As + sck * 8 + kb;
  const u16* Bg = Bw + (size_t)(n0 + srow) * K + sck * 8 + kb;

  for (int k0 = 0; k0 < kchunk; k0 += 32) {
#pragma unroll
    for (int it = 0; it < NCA; ++it)
      GLDS16(Ag + (size_t)it * 64 * As + k0, &lA[(it * 256 + tid) * 8]);
#pragma unroll
    for (int it = 0; it < NCB; ++it)
      GLDS16(Bg + (size_t)it * 64 * K + k0, &lB[(it * 256 + tid) * 8]);
    __syncthreads();
    bf16x8 af[MF], bfr[NF];
    const int koff = (lane >> 4) * 8;
#pragma unroll
    for (int mi = 0; mi < MF; ++mi) {
      int r = wr * (MF * 16) + mi * 16 + (lane & 15);
      af[mi] = *(const bf16x8*)(&lA[r * 32 + koff]);
    }
#pragma unroll
    for (int ni = 0; ni < NF; ++ni) {
      int r = wc * (NF * 16) + ni * 16 + (lane & 15);
      bfr[ni] = *(const bf16x8*)(&lB[r * 32 + koff]);
    }
#pragma unroll
    for (int mi = 0; mi < MF; ++mi)
#pragma unroll
      for (int ni = 0; ni < NF; ++ni)
        acc[mi][ni] = __builtin_amdgcn_mfma_f32_16x16x32_bf16(af[mi], bfr[ni], acc[mi][ni], 0, 0, 0);
    __syncthreads();
  }

  float* co = Cf + (size_t)blockIdx.z * (size_t)M * N;
  const int rbase = (lane >> 4) * 4;
  const int cbase = lane & 15;
#pragma unroll
  for (int mi = 0; mi < MF; ++mi) {
#pragma unroll
    for (int ni = 0; ni < NF; ++ni) {
      int row = m0 + wr * (MF * 16) + mi * 16 + rbase;
      int col = n0 + wc * (NF * 16) + ni * 16 + cbase;
      float bv = 0.f;
      if (EPI == 2 || EPI == 3) bv = bias[col];
      if (EPI == 4) bv = (col < 256) ? bias[col] : bias2[col - 256];
#pragma unroll
      for (int r = 0; r < 4; ++r) {
        float v = acc[mi][ni][r] + bv;
        if (EPI == 2 || EPI == 4) v = fmaxf(v, 0.f);
        size_t idx = (size_t)(row + r) * N + col;
        if (EPI == 1 || EPI == 2 || EPI == 4) Cb[idx] = f2b(v);
        else co[idx] = v;
      }
    }
  }
}

// ------- causal depthwise conv(K=4) + silu, 8 d/thread, writes f32 + bf16 -----
__global__ __launch_bounds__(256) void conv_silu_f(
    const u16* __restrict__ xz, const float* __restrict__ cwT,
    const float* __restrict__ cb, float* __restrict__ xcf, u16* __restrict__ xcb) {
  int gid = blockIdx.x * 256 + threadIdx.x;     // over 4*1024*128 groups
  int d0 = (gid & 127) * 8;
  int token = gid >> 7;
  int t = token & 1023;
  const u16* xx = xz + (size_t)(token - t) * 2048 + d0;
  float s[8];
  {
    float4 cba = *(const float4*)(cb + d0);
    float4 cbb = *(const float4*)(cb + d0 + 4);
    s[0] = cba.x; s[1] = cba.y; s[2] = cba.z; s[3] = cba.w;
    s[4] = cbb.x; s[5] = cbb.y; s[6] = cbb.z; s[7] = cbb.w;
  }
#pragma unroll
  for (int k = 0; k < 4; ++k) {
    int tt = t - 3 + k;
    if (tt >= 0) {
      u16x8 v = *(const u16x8*)(xx + (size_t)tt * 2048);
      float4 wA = *(const float4*)(cwT + (size_t)k * 1024 + d0);
      float4 wB = *(const float4*)(cwT + (size_t)k * 1024 + d0 + 4);
      s[0] += wA.x * b2f(v[0]); s[1] += wA.y * b2f(v[1]);
      s[2] += wA.z * b2f(v[2]); s[3] += wA.w * b2f(v[3]);
      s[4] += wB.x * b2f(v[4]); s[5] += wB.y * b2f(v[5]);
      s[6] += wB.z * b2f(v[6]); s[7] += wB.w * b2f(v[7]);
    }
  }
  u16x8 o;
  float4 fa, fb;
#pragma unroll
  for (int j = 0; j < 8; ++j) {
    float sl = s[j] / (1.f + expf(-s[j]));
    s[j] = sl;
    o[j] = f2b(sl);
  }
  fa.x = s[0]; fa.y = s[1]; fa.z = s[2]; fa.w = s[3];
  fb.x = s[4]; fb.y = s[5]; fb.z = s[6]; fb.w = s[7];
  *(float4*)(xcf + (size_t)token * 1024 + d0) = fa;
  *(float4*)(xcf + (size_t)token * 1024 + d0 + 4) = fb;
  *(u16x8*)(xcb + (size_t)token * 1024 + d0) = o;
}

// ---------------- reduce x_proj partials + dt = softplus(...) (f32) ----------
__global__ __launch_bounds__(256) void dt_kernel2(
    const float* __restrict__ P, const float* __restrict__ dpwT,
    const float* __restrict__ dpb, float* __restrict__ dtout,
    float* __restrict__ dbcr) {
  const int tid = threadIdx.x;
  const int tok0 = blockIdx.x * 16;
  __shared__ float sm[16][64];
  const size_t str = (size_t)4096 * 64;
  for (int i = tid; i < 16 * 64; i += 256) {
    size_t o = (size_t)tok0 * 64 + i;
    float v = P[o] + P[str + o] + P[2 * str + o] + P[3 * str + o];
    ((float*)sm)[i] = v;
    dbcr[o] = v;
  }
  __syncthreads();
  float acc0[16], acc1[16], acc2[16], acc3[16];
#pragma unroll
  for (int t = 0; t < 16; ++t) { acc0[t] = 0.f; acc1[t] = 0.f; acc2[t] = 0.f; acc3[t] = 0.f; }
#pragma unroll 4
  for (int j = 0; j < 32; ++j) {
    float w0 = dpwT[(size_t)j * 1024 + tid];
    float w1 = dpwT[(size_t)j * 1024 + 256 + tid];
    float w2 = dpwT[(size_t)j * 1024 + 512 + tid];
    float w3 = dpwT[(size_t)j * 1024 + 768 + tid];
#pragma unroll
    for (int t = 0; t < 16; ++t) {
      float sv = sm[t][j];
      acc0[t] += sv * w0;
      acc1[t] += sv * w1;
      acc2[t] += sv * w2;
      acc3[t] += sv * w3;
    }
  }
  const float b0 = dpb[tid], b1 = dpb[256 + tid], b2 = dpb[512 + tid], b3 = dpb[768 + tid];
#pragma unroll
  for (int t = 0; t < 16; ++t) {
    size_t o = (size_t)(tok0 + t) * 1024 + tid;
    float a0 = acc0[t] + b0, a1 = acc1[t] + b1, a2 = acc2[t] + b2, a3 = acc3[t] + b3;
    dtout[o]       = (a0 > 20.f) ? a0 : logf(1.f + expf(a0));
    dtout[o + 256] = (a1 > 20.f) ? a1 : logf(1.f + expf(a1));
    dtout[o + 512] = (a2 > 20.f) ? a2 : logf(1.f + expf(a2));
    dtout[o + 768] = (a3 > 20.f) ? a3 : logf(1.f + expf(a3));
  }
}

// ---------------- chunked selective scan, lane-owns-d (round-6 verbatim) -----
// E/U/H0 layout: [b][c][n][d] (d innermost, coalesced).
__global__ __launch_bounds__(256) void scan1(
    const float* __restrict__ dt, const float* __restrict__ xc,
    const float* __restrict__ dbc, const float* __restrict__ Alog,
    float* __restrict__ Ebuf, float* __restrict__ Ubuf, int NCc, int TCc) {
  const int d = blockIdx.x * 256 + threadIdx.x;
  const int c = blockIdx.y;
  const int b = blockIdx.z;
  const int t0 = c * TCc;
  __shared__ __align__(16) float sB[64][16];
  for (int i = threadIdx.x; i < TCc * 16; i += 256) {
    int t = i >> 4, n = i & 15;
    sB[t][n] = dbc[((size_t)(b * 1024 + t0 + t)) * 64 + 32 + n];
  }
  float A2[16];
#pragma unroll
  for (int q = 0; q < 4; ++q) {
    float4 a4 = *(const float4*)(Alog + (size_t)d * 16 + q * 4);
    A2[q * 4 + 0] = -expf(a4.x) * 1.4426950408889634f;
    A2[q * 4 + 1] = -expf(a4.y) * 1.4426950408889634f;
    A2[q * 4 + 2] = -expf(a4.z) * 1.4426950408889634f;
    A2[q * 4 + 3] = -expf(a4.w) * 1.4426950408889634f;
  }
  __syncthreads();
  float hc[16];
#pragma unroll
  for (int n = 0; n < 16; ++n) hc[n] = 0.f;
  float sumdt = 0.f;
  size_t tok = (size_t)b * 1024 + t0;
  for (int t = 0; t < TCc; ++t, ++tok) {
    float dtv = dt[tok * 1024 + d];
    float xcv = xc[tok * 1024 + d];
    float du = dtv * xcv;
    sumdt += dtv;
#pragma unroll
    for (int q = 0; q < 4; ++q) {
      float4 B4 = *(const float4*)(&sB[t][q * 4]);
      float e0 = exp2f(dtv * A2[q * 4 + 0]);
      float e1 = exp2f(dtv * A2[q * 4 + 1]);
      float e2 = exp2f(dtv * A2[q * 4 + 2]);
      float e3 = exp2f(dtv * A2[q * 4 + 3]);
      hc[q * 4 + 0] = e0 * hc[q * 4 + 0] + du * B4.x;
      hc[q * 4 + 1] = e1 * hc[q * 4 + 1] + du * B4.y;
      hc[q * 4 + 2] = e2 * hc[q * 4 + 2] + du * B4.z;
      hc[q * 4 + 3] = e3 * hc[q * 4 + 3] + du * B4.w;
    }
  }
  size_t ob = (((size_t)b * NCc + c) * 16) * 1024 + d;
#pragma unroll
  for (int n = 0; n < 16; ++n) {
    Ebuf[ob + (size_t)n * 1024] = exp2f(A2[n] * sumdt);
    Ubuf[ob + (size_t)n * 1024] = hc[n];
  }
}

__global__ __launch_bounds__(256) void scan_mid(
    const float* __restrict__ Ebuf, const float* __restrict__ Ubuf,
    float* __restrict__ H0, int NCc) {
  int idx = blockIdx.x * 256 + threadIdx.x;   // b*16384 + n*1024 + d
  int b = idx >> 14;
  int nd = idx & 16383;
  float h = 0.f;
  size_t o0 = ((size_t)b * NCc * 16) * 1024 + nd;
  const size_t cstr = (size_t)16 * 1024;
  for (int cc = 0; cc < NCc; ++cc) {
    size_t o = o0 + (size_t)cc * cstr;
    H0[o] = h;
    if (cc < NCc - 1) h = Ebuf[o] * h + Ubuf[o];
  }
}

__global__ __launch_bounds__(256) void scan2(
    const float* __restrict__ dt, const float* __restrict__ xc,
    const float* __restrict__ dbc, const u16* __restrict__ xz,
    const float* __restrict__ Alog, const float* __restrict__ Dp,
    const float* __restrict__ H0, u16* __restrict__ yg, int NCc, int TCc) {
  const int d = blockIdx.x * 256 + threadIdx.x;
  const int c = blockIdx.y;
  const int b = blockIdx.z;
  const int t0 = c * TCc;
  __shared__ __align__(16) float sB[64][16];
  __shared__ __align__(16) float sC[64][16];
  for (int i = threadIdx.x; i < TCc * 16; i += 256) {
    int t = i >> 4, n = i & 15;
    size_t o = ((size_t)(b * 1024 + t0 + t)) * 64 + 32;
    sB[t][n] = dbc[o + n];
    sC[t][n] = dbc[o + 16 + n];
  }
  float A2[16];
#pragma unroll
  for (int q = 0; q < 4; ++q) {
    float4 a4 = *(const float4*)(Alog + (size_t)d * 16 + q * 4);
    A2[q * 4 + 0] = -expf(a4.x) * 1.4426950408889634f;
    A2[q * 4 + 1] = -expf(a4.y) * 1.4426950408889634f;
    A2[q * 4 + 2] = -expf(a4.z) * 1.4426950408889634f;
    A2[q * 4 + 3] = -expf(a4.w) * 1.4426950408889634f;
  }
  const float Dd = Dp[d];
  float hc[16];
  size_t ob = (((size_t)b * NCc + c) * 16) * 1024 + d;
#pragma unroll
  for (int n = 0; n < 16; ++n) hc[n] = H0[ob + (size_t)n * 1024];
  __syncthreads();
  size_t tok = (size_t)b * 1024 + t0;
  for (int t = 0; t < TCc; ++t, ++tok) {
    float dtv = dt[tok * 1024 + d];
    float xcv = xc[tok * 1024 + d];
    float du = dtv * xcv;
    float y0 = 0.f, y1 = 0.f, y2 = 0.f, y3 = 0.f;
#pragma unroll
    for (int q = 0; q < 4; ++q) {
      float4 B4 = *(const float4*)(&sB[t][q * 4]);
      float4 C4 = *(const float4*)(&sC[t][q * 4]);
      float e0 = exp2f(dtv * A2[q * 4 + 0]);
      float e1 = exp2f(dtv * A2[q * 4 + 1]);
      float e2 = exp2f(dtv * A2[q * 4 + 2]);
      float e3 = exp2f(dtv * A2[q * 4 + 3]);
      hc[q * 4 + 0] = e0 * hc[q * 4 + 0] + du * B4.x;
      hc[q * 4 + 1] = e1 * hc[q * 4 + 1] + du * B4.y;
      hc[q * 4 + 2] = e2 * hc[q * 4 + 2] + du * B4.z;
      hc[q * 4 + 3] = e3 * hc[q * 4 + 3] + du * B4.w;
      y0 += hc[q * 4 + 0] * C4.x;
      y1 += hc[q * 4 + 1] * C4.y;
      y2 += hc[q * 4 + 2] * C4.z;
      y3 += hc[q * 4 + 3] * C4.w;
    }
    float y = (y0 + y1) + (y2 + y3);
    float z = b2f(xz[tok * 2048 + 1024 + d]);
    float g = z / (1.f + expf(-z));
    yg[tok * 1024 + d] = f2b((y + Dd * xcv) * g);
  }
}

// ---------------- reward head: out = t1sr[:,256:] @ ro_w2^T + b --------------
__global__ __launch_bounds__(256) void reward_head_kernel(
    const u16* __restrict__ t1sr, const float* __restrict__ w2,
    const float* __restrict__ b2, float* __restrict__ outr) {
  int tok = blockIdx.x * 4 + (threadIdx.x >> 6);
  int lane = threadIdx.x & 63;
  float s = 0.f;
#pragma unroll
  for (int j = 0; j < 256; j += 64)
    s += b2f(t1sr[(size_t)tok * 512 + 256 + j + lane]) * w2[j + lane];
#pragma unroll
  for (int o = 32; o; o >>= 1) s += __shfl_xor(s, o);
  if (lane == 0) outr[tok] = s + b2[0];
}

extern "C" void kernel_launch(void* const* d_in, const int* in_sizes, int n_in,
                              void* d_out, int out_size, void* d_ws, size_t ws_size,
                              hipStream_t stream) {
  const float* x    = (const float*)d_in[0];
  const float* rtg  = (const float*)d_in[1];
  const float* Wse  = (const float*)d_in[2];
  const float* bse  = (const float*)d_in[3];
  const float* Wre  = (const float*)d_in[4];
  const float* bre  = (const float*)d_in[5];
  const float* lnw  = (const float*)d_in[6];
  const float* lnb  = (const float*)d_in[7];
  const float* ipw  = (const float*)d_in[8];
  const float* cw   = (const float*)d_in[9];
  const float* cb   = (const float*)d_in[10];
  const float* xpw  = (const float*)d_in[11];
  const float* dpw  = (const float*)d_in[12];
  const float* dpb  = (const float*)d_in[13];
  const float* Alog = (const float*)d_in[14];
  const float* Dp   = (const float*)d_in[15];
  const float* opw  = (const float*)d_in[16];
  const float* nw   = (const float*)d_in[17];
  const float* nfw  = (const float*)d_in[18];
  const float* sow1 = (const float*)d_in[19];
  const float* sob1 = (const float*)d_in[20];
  const float* sow2 = (const float*)d_in[21];
  const float* sob2 = (const float*)d_in[22];
  const float* row1 = (const float*)d_in[23];
  const float* rob1 = (const float*)d_in[24];
  const float* row2 = (const float*)d_in[25];
  const float* rob2 = (const float*)d_in[26];
  (void)in_sizes; (void)n_in; (void)out_size;

  char* wsp = (char*)d_ws;
  size_t off = 0;
  auto alloc = [&](size_t bytes) -> void* {
    off = (off + 255) & ~(size_t)255;
    void* p = wsp + off;
    off += bytes;
    return p;
  };
  const int TOK = 4096;
  float* h     = (float*)alloc((size_t)TOK * 512 * 4);
  float* resid = (float*)alloc((size_t)TOK * 512 * 4);
  u16* hn      = (u16*)alloc((size_t)TOK * 512 * 2);
  u16* xzb     = (u16*)alloc((size_t)TOK * 2048 * 2);
  float* xcf   = (float*)alloc((size_t)TOK * 1024 * 4);
  u16* xcb     = (u16*)alloc((size_t)TOK * 1024 * 2);   // conv bf16; scan2 overwrites w/ gated y
  float* dbcP  = (float*)alloc((size_t)4 * TOK * 64 * 4);
  float* dbc   = (float*)alloc((size_t)TOK * 64 * 4);
  float* dtf   = (float*)alloc((size_t)TOK * 1024 * 4);
  float* PEt   = (float*)alloc((size_t)1024 * 512 * 4);
  float* dpwT  = (float*)alloc((size_t)4 * 32 * 1024 * 4);
  float* cwT   = (float*)alloc((size_t)4 * 4 * 1024 * 4);
  u16* ipwb    = (u16*)alloc((size_t)4 * 2048 * 512 * 2);
  u16* xpwb    = (u16*)alloc((size_t)4 * 64 * 1024 * 2);
  u16* opwb    = (u16*)alloc((size_t)4 * 512 * 1024 * 2);
  u16* sow1b   = (u16*)alloc((size_t)256 * 512 * 2);    // sow1b/row1b adjacent (merged head)
  u16* row1b   = (u16*)alloc((size_t)256 * 512 * 2);
  u16* sow2b   = (u16*)alloc((size_t)128 * 256 * 2);

  // pick NC by available workspace (deterministic in ws_size -> graph-safe)
  size_t base_off = (off + 255) & ~(size_t)255;
  auto scan_bytes = [](int nc) {
    return (size_t)3 * 4 * nc * 16 * 1024 * 4 + 512;
  };
  int NCc = 16;
  if (ws_size >= base_off + scan_bytes(64)) NCc = 64;
  else if (ws_size >= base_off + scan_bytes(32)) NCc = 32;
  int TCc = 1024 / NCc;
  // E/U (scan chunk state) aliased with t1sr (head temp, post-layer only)
  char* shared8 = (char*)alloc((size_t)2 * 4096 * NCc * 16 * 4);
  float* Ebuf  = (float*)shared8;
  float* Ubuf  = Ebuf + (size_t)4096 * NCc * 16;
  float* H0    = (float*)alloc((size_t)4096 * NCc * 16 * 4);
  u16* t1sr    = (u16*)shared8;                          // [4096][512] bf16

  setup_kernel<<<29376, 256, 0, stream>>>(ipw, ipwb, xpw, xpwb, opw, opwb,
                                          sow1, sow1b, sow2, sow2b, row1, row1b,
                                          PEt, dpw, dpwT, cw, cwT);
  embed_ln2<<<256, 256, 0, stream>>>(x, rtg, Wse, bse, Wre, bre, lnw, lnb, PEt, h);

  for (int i = 0; i < 4; ++i) {
    resid_rms_kernel<<<TOK, 256, 0, stream>>>(h, resid, nw + i * 512, hn, i == 0);
    gemm_bt<128, 128, 2, 2, 1><<<dim3(32, 16, 1), 256, 0, stream>>>(
        hn, ipwb + (size_t)i * 2048 * 512, nullptr, xzb, nullptr, nullptr,
        4096, 2048, 512, 512);
    conv_silu_f<<<2048, 256, 0, stream>>>(
        xzb, cwT + (size_t)i * 4096, cb + i * 1024, xcf, xcb);
    gemm_bt<128, 64, 2, 2, 0><<<dim3(32, 1, 4), 256, 0, stream>>>(
        xcb, xpwb + (size_t)i * 64 * 1024, dbcP, nullptr, nullptr, nullptr,
        4096, 64, 1024, 1024);
    dt_kernel2<<<TOK / 16, 256, 0, stream>>>(dbcP, dpwT + (size_t)i * 32 * 1024,
                                             dpb + i * 1024, dtf, dbc);
    scan1<<<dim3(4, NCc - 1, 4), 256, 0, stream>>>(
        dtf, xcf, dbc, Alog + (size_t)i * 1024 * 16, Ebuf, Ubuf, NCc, TCc);
    scan_mid<<<256, 256, 0, stream>>>(Ebuf, Ubuf, H0, NCc);
    scan2<<<dim3(4, NCc, 4), 256, 0, stream>>>(
        dtf, xcf, dbc, xzb, Alog + (size_t)i * 1024 * 16, Dp + i * 1024,
        H0, xcb, NCc, TCc);
    gemm_bt<128, 64, 2, 2, 0><<<dim3(32, 8, 1), 256, 0, stream>>>(
        xcb, opwb + (size_t)i * 512 * 1024, h, nullptr, nullptr, nullptr,
        4096, 512, 1024, 1024);
  }

  resid_rms_kernel<<<TOK, 256, 0, stream>>>(h, resid, nfw, hn, 0);
  gemm_bt<64, 64, 2, 2, 4><<<dim3(64, 8, 1), 256, 0, stream>>>(
      hn, sow1b, nullptr, t1sr, sob1, rob1, 4096, 512, 512, 512);
  gemm_bt<64, 64, 2, 2, 3><<<dim3(64, 2, 1), 256, 0, stream>>>(
      t1sr, sow2b, (float*)d_out, nullptr, sob2, nullptr, 4096, 128, 256, 512);
  reward_head_kernel<<<TOK / 4, 256, 0, stream>>>(
      t1sr, row2, rob2, (float*)d_out + (size_t)TOK * 128);
}

// Round 13
// 649.197 us; speedup vs baseline: 1.0371x; 1.0371x over previous
//
#include <hip/hip_runtime.h>
#include <stdint.h>

typedef unsigned short u16;
typedef __attribute__((ext_vector_type(8))) short bf16x8;
typedef __attribute__((ext_vector_type(8))) u16 u16x8;
typedef __attribute__((ext_vector_type(4))) float f32x4;

static __device__ __forceinline__ u16 f2b(float f) {
  uint32_t u = __builtin_bit_cast(uint32_t, f);
  u += 0x7fffu + ((u >> 16) & 1u);
  return (u16)(u >> 16);
}
static __device__ __forceinline__ float b2f(u16 h) {
  uint32_t u = ((uint32_t)h) << 16;
  return __builtin_bit_cast(float, u);
}

#define GLDS16(gsrc, ldst)                                                        \
  __builtin_amdgcn_global_load_lds(                                               \
      (const __attribute__((address_space(1))) void*)(gsrc),                      \
      (__attribute__((address_space(3))) void*)(ldst), 16, 0, 0)

// ---------------- all setup work in ONE kernel ----------------
// segments: 6 weight casts, PE table, dpw transpose, cw transpose, A2T table
__global__ __launch_bounds__(256) void setup_kernel(
    const float* __restrict__ ipw, u16* __restrict__ ipwb,
    const float* __restrict__ xpw, u16* __restrict__ xpwb,
    const float* __restrict__ opw, u16* __restrict__ opwb,
    const float* __restrict__ sow1, u16* __restrict__ sow1b,
    const float* __restrict__ sow2, u16* __restrict__ sow2b,
    const float* __restrict__ row1, u16* __restrict__ row1b,
    float* __restrict__ PEt,
    const float* __restrict__ dpw, float* __restrict__ dpwT,
    const float* __restrict__ cw, float* __restrict__ cwT,
    const float* __restrict__ Alog, float* __restrict__ A2T) {
  int i = blockIdx.x * 256 + threadIdx.x;
  if (i < 4194304) { ipwb[i] = f2b(ipw[i]); return; } i -= 4194304;
  if (i < 262144)  { xpwb[i] = f2b(xpw[i]); return; } i -= 262144;
  if (i < 2097152) { opwb[i] = f2b(opw[i]); return; } i -= 2097152;
  if (i < 131072)  { sow1b[i] = f2b(sow1[i]); return; } i -= 131072;
  if (i < 32768)   { sow2b[i] = f2b(sow2[i]); return; } i -= 32768;
  if (i < 131072)  { row1b[i] = f2b(row1[i]); return; } i -= 131072;
  if (i < 524288) {  // PE: i = l*512 + dd
    int dd = i & 511, l = i >> 9;
    const float cc = -9.210340371976184f / 512.f;
    float div = expf((float)(2 * (dd >> 1)) * cc);
    PEt[i] = (dd & 1) ? cosf((float)l * div) : sinf((float)l * div);
    return;
  } i -= 524288;
  if (i < 131072) {  // dpwT[l][j][dd] = dpw[l][dd][j]
    int l = i >> 15, r = i & 32767, j = r >> 10, dd = r & 1023;
    dpwT[i] = dpw[(size_t)l * 32768 + (size_t)dd * 32 + j];
    return;
  } i -= 131072;
  if (i < 16384) {   // cwT[l][k][dd] = cw[l][dd][k]
    int l = i >> 12, r = i & 4095, k = r >> 10, dd = r & 1023;
    cwT[i] = cw[(size_t)l * 4096 + (size_t)dd * 4 + k];
    return;
  } i -= 16384;
  if (i < 65536) {   // A2T[l][n][d] = -exp(Alog[l][d][n]) * log2(e)
    int l = i >> 14, r = i & 16383, n = r >> 10, d = r & 1023;
    A2T[i] = -expf(Alog[(size_t)l * 16384 + (size_t)d * 16 + n]) * 1.4426950408889634f;
  }
}

// ---------------- embedding + PE + LayerNorm (16 tokens/block) ----------------
__global__ __launch_bounds__(256) void embed_ln2(
    const float* __restrict__ x, const float* __restrict__ rtg,
    const float* __restrict__ Wse, const float* __restrict__ bse,
    const float* __restrict__ Wre, const float* __restrict__ bre,
    const float* __restrict__ lnw, const float* __restrict__ lnb,
    const float* __restrict__ PEt, float* __restrict__ h) {
  const int tid = threadIdx.x;
  const int tok0 = blockIdx.x * 16;
  const int l0 = tok0 & 1023;
  __shared__ float xs[16][128];
  __shared__ float rt[16];
  __shared__ float sw[16][2][4];
  for (int i = tid; i < 16 * 128; i += 256) ((float*)xs)[i] = x[(size_t)tok0 * 128 + i];
  if (tid < 16) rt[tid] = rtg[tok0 + tid];
  __syncthreads();
  const int d = tid;
  float acc[16];
#pragma unroll
  for (int tt = 0; tt < 16; ++tt) acc[tt] = 0.f;
  const float* wrow = Wse + (size_t)d * 128;
  for (int k0 = 0; k0 < 128; k0 += 8) {
    float4 wa = *(const float4*)(wrow + k0);
    float4 wb = *(const float4*)(wrow + k0 + 4);
#pragma unroll
    for (int tt = 0; tt < 16; ++tt) {
      const float* xr = &xs[tt][k0];
      acc[tt] += xr[0] * wa.x + xr[1] * wa.y + xr[2] * wa.z + xr[3] * wa.w +
                 xr[4] * wb.x + xr[5] * wb.y + xr[6] * wb.z + xr[7] * wb.w;
    }
  }
  const float seb = bse[d], reW = Wre[d], reB = bre[d];
  const int lane = tid & 63, wv = tid >> 6;
  float h1a[16];
#pragma unroll
  for (int tt = 0; tt < 16; ++tt) {
    float h0 = acc[tt] + seb + PEt[(size_t)(l0 + tt) * 512 + d];
    float h1 = reB + rt[tt] * reW + PEt[(size_t)(l0 + tt) * 512 + 256 + d];
    acc[tt] = h0;
    h1a[tt] = h1;
    float s = h0 + h1, q = h0 * h0 + h1 * h1;
#pragma unroll
    for (int o = 32; o; o >>= 1) { s += __shfl_xor(s, o); q += __shfl_xor(q, o); }
    if (lane == 0) { sw[tt][0][wv] = s; sw[tt][1][wv] = q; }
  }
  __syncthreads();
#pragma unroll
  for (int tt = 0; tt < 16; ++tt) {
    float S = sw[tt][0][0] + sw[tt][0][1] + sw[tt][0][2] + sw[tt][0][3];
    float Q = sw[tt][1][0] + sw[tt][1][1] + sw[tt][1][2] + sw[tt][1][3];
    float mean = S * (1.f / 512.f);
    float var = Q * (1.f / 512.f) - mean * mean;
    float rstd = rsqrtf(var + 1e-5f);
    size_t base = (size_t)(tok0 + tt) * 512;
    h[base + d]       = (acc[tt] - mean) * rstd * lnw[d] + lnb[d];
    h[base + 256 + d] = (h1a[tt] - mean) * rstd * lnw[256 + d] + lnb[256 + d];
  }
}

// ---------------- residual add + RMSNorm -> bf16 ----------------
__global__ __launch_bounds__(256) void resid_rms_kernel(
    const float* __restrict__ hin, float* __restrict__ residual,
    const float* __restrict__ w, u16* __restrict__ outb, int first) {
  const int tok = blockIdx.x;
  const int t = threadIdx.x;
  __shared__ float rq[4];
  size_t base = (size_t)tok * 512;
  float v0 = hin[base + t], v1 = hin[base + t + 256];
  if (!first) { v0 += residual[base + t]; v1 += residual[base + t + 256]; }
  residual[base + t] = v0;
  residual[base + t + 256] = v1;
  float q = v0 * v0 + v1 * v1;
#pragma unroll
  for (int o = 32; o; o >>= 1) q += __shfl_xor(q, o);
  if ((t & 63) == 0) rq[t >> 6] = q;
  __syncthreads();
  float Q = rq[0] + rq[1] + rq[2] + rq[3];
  float scale = rsqrtf(Q * (1.f / 512.f) + 1e-5f);
  outb[base + t]       = f2b(v0 * scale * w[t]);
  outb[base + t + 256] = f2b(v1 * scale * w[t + 256]);
}

// ---------------- MFMA GEMM: C[M,N] = A[M,K] * Bw[N,K]^T ----------------
// As = A row stride. EPI: 0=f32, 1=bf16, 2=bias+relu->bf16, 3=bias->f32,
// 4=dual-bias+relu->bf16 (bias[col<256], bias2[col-256])
template <int BM, int BN, int WM, int WN, int EPI>
__global__ __launch_bounds__(256) void gemm_bt(
    const u16* __restrict__ A, const u16* __restrict__ Bw,
    float* __restrict__ Cf, u16* __restrict__ Cb,
    const float* __restrict__ bias, const float* __restrict__ bias2,
    int M, int N, int K, int As) {
  constexpr int MF = BM / (WM * 16);
  constexpr int NF = BN / (WN * 16);
  constexpr int NCA = (BM * 4) / 256;
  constexpr int NCB = (BN * 4) / 256;
  __shared__ __align__(16) u16 lA[BM * 32];
  __shared__ __align__(16) u16 lB[BN * 32];
  const int tid = threadIdx.x;
  const int lane = tid & 63;
  const int wv = tid >> 6;
  const int wr = wv / WN, wc = wv % WN;
  const int m0 = blockIdx.x * BM, n0 = blockIdx.y * BN;
  const int kchunk = K / gridDim.z;
  const int kb = blockIdx.z * kchunk;

  f32x4 acc[MF][NF];
#pragma unroll
  for (int i = 0; i < MF; ++i)
#pragma unroll
    for (int j = 0; j < NF; ++j) acc[i][j] = (f32x4){0.f, 0.f, 0.f, 0.f};

  const int srow = tid >> 2, sck = tid & 3;
  const u16* Ag = A + (size_t)(m0 + srow) * As + sck * 8 + kb;
  const u16* Bg = Bw + (size_t)(n0 + srow) * K + sck * 8 + kb;

  for (int k0 = 0; k0 < kchunk; k0 += 32) {
#pragma unroll
    for (int it = 0; it < NCA; ++it)
      GLDS16(Ag + (size_t)it * 64 * As + k0, &lA[(it * 256 + tid) * 8]);
#pragma unroll
    for (int it = 0; it < NCB; ++it)
      GLDS16(Bg + (size_t)it * 64 * K + k0, &lB[(it * 256 + tid) * 8]);
    __syncthreads();
    bf16x8 af[MF], bfr[NF];
    const int koff = (lane >> 4) * 8;
#pragma unroll
    for (int mi = 0; mi < MF; ++mi) {
      int r = wr * (MF * 16) + mi * 16 + (lane & 15);
      af[mi] = *(const bf16x8*)(&lA[r * 32 + koff]);
    }
#pragma unroll
    for (int ni = 0; ni < NF; ++ni) {
      int r = wc * (NF * 16) + ni * 16 + (lane & 15);
      bfr[ni] = *(const bf16x8*)(&lB[r * 32 + koff]);
    }
#pragma unroll
    for (int mi = 0; mi < MF; ++mi)
#pragma unroll
      for (int ni = 0; ni < NF; ++ni)
        acc[mi][ni] = __builtin_amdgcn_mfma_f32_16x16x32_bf16(af[mi], bfr[ni], acc[mi][ni], 0, 0, 0);
    __syncthreads();
  }

  float* co = Cf + (size_t)blockIdx.z * (size_t)M * N;
  const int rbase = (lane >> 4) * 4;
  const int cbase = lane & 15;
#pragma unroll
  for (int mi = 0; mi < MF; ++mi) {
#pragma unroll
    for (int ni = 0; ni < NF; ++ni) {
      int row = m0 + wr * (MF * 16) + mi * 16 + rbase;
      int col = n0 + wc * (NF * 16) + ni * 16 + cbase;
      float bv = 0.f;
      if (EPI == 2 || EPI == 3) bv = bias[col];
      if (EPI == 4) bv = (col < 256) ? bias[col] : bias2[col - 256];
#pragma unroll
      for (int r = 0; r < 4; ++r) {
        float v = acc[mi][ni][r] + bv;
        if (EPI == 2 || EPI == 4) v = fmaxf(v, 0.f);
        size_t idx = (size_t)(row + r) * N + col;
        if (EPI == 1 || EPI == 2 || EPI == 4) Cb[idx] = f2b(v);
        else co[idx] = v;
      }
    }
  }
}

// ------- causal depthwise conv(K=4) + silu, 8 d/thread, writes f32 + bf16 -----
__global__ __launch_bounds__(256) void conv_silu_f(
    const u16* __restrict__ xz, const float* __restrict__ cwT,
    const float* __restrict__ cb, float* __restrict__ xcf, u16* __restrict__ xcb) {
  int gid = blockIdx.x * 256 + threadIdx.x;     // over 4*1024*128 groups
  int d0 = (gid & 127) * 8;
  int token = gid >> 7;
  int t = token & 1023;
  const u16* xx = xz + (size_t)(token - t) * 2048 + d0;
  float s[8];
  {
    float4 cba = *(const float4*)(cb + d0);
    float4 cbb = *(const float4*)(cb + d0 + 4);
    s[0] = cba.x; s[1] = cba.y; s[2] = cba.z; s[3] = cba.w;
    s[4] = cbb.x; s[5] = cbb.y; s[6] = cbb.z; s[7] = cbb.w;
  }
#pragma unroll
  for (int k = 0; k < 4; ++k) {
    int tt = t - 3 + k;
    if (tt >= 0) {
      u16x8 v = *(const u16x8*)(xx + (size_t)tt * 2048);
      float4 wA = *(const float4*)(cwT + (size_t)k * 1024 + d0);
      float4 wB = *(const float4*)(cwT + (size_t)k * 1024 + d0 + 4);
      s[0] += wA.x * b2f(v[0]); s[1] += wA.y * b2f(v[1]);
      s[2] += wA.z * b2f(v[2]); s[3] += wA.w * b2f(v[3]);
      s[4] += wB.x * b2f(v[4]); s[5] += wB.y * b2f(v[5]);
      s[6] += wB.z * b2f(v[6]); s[7] += wB.w * b2f(v[7]);
    }
  }
  u16x8 o;
  float4 fa, fb;
#pragma unroll
  for (int j = 0; j < 8; ++j) {
    float sl = s[j] / (1.f + expf(-s[j]));
    s[j] = sl;
    o[j] = f2b(sl);
  }
  fa.x = s[0]; fa.y = s[1]; fa.z = s[2]; fa.w = s[3];
  fb.x = s[4]; fb.y = s[5]; fb.z = s[6]; fb.w = s[7];
  *(float4*)(xcf + (size_t)token * 1024 + d0) = fa;
  *(float4*)(xcf + (size_t)token * 1024 + d0 + 4) = fb;
  *(u16x8*)(xcb + (size_t)token * 1024 + d0) = o;
}

// ---- reduce x_proj partials (8-way K-split) + dt = softplus(...) (f32) ------
__global__ __launch_bounds__(256) void dt_kernel2(
    const float* __restrict__ P, const float* __restrict__ dpwT,
    const float* __restrict__ dpb, float* __restrict__ dtout,
    float* __restrict__ dbcr) {
  const int tid = threadIdx.x;
  const int tok0 = blockIdx.x * 16;
  __shared__ float sm[16][64];
  const size_t str = (size_t)4096 * 64;
  for (int i = tid; i < 16 * 64; i += 256) {
    size_t o = (size_t)tok0 * 64 + i;
    float v = 0.f;
#pragma unroll
    for (int p = 0; p < 8; ++p) v += P[(size_t)p * str + o];
    ((float*)sm)[i] = v;
    dbcr[o] = v;
  }
  __syncthreads();
  float acc0[16], acc1[16], acc2[16], acc3[16];
#pragma unroll
  for (int t = 0; t < 16; ++t) { acc0[t] = 0.f; acc1[t] = 0.f; acc2[t] = 0.f; acc3[t] = 0.f; }
#pragma unroll 4
  for (int j = 0; j < 32; ++j) {
    float w0 = dpwT[(size_t)j * 1024 + tid];
    float w1 = dpwT[(size_t)j * 1024 + 256 + tid];
    float w2 = dpwT[(size_t)j * 1024 + 512 + tid];
    float w3 = dpwT[(size_t)j * 1024 + 768 + tid];
#pragma unroll
    for (int t = 0; t < 16; ++t) {
      float sv = sm[t][j];
      acc0[t] += sv * w0;
      acc1[t] += sv * w1;
      acc2[t] += sv * w2;
      acc3[t] += sv * w3;
    }
  }
  const float b0 = dpb[tid], b1 = dpb[256 + tid], b2 = dpb[512 + tid], b3 = dpb[768 + tid];
#pragma unroll
  for (int t = 0; t < 16; ++t) {
    size_t o = (size_t)(tok0 + t) * 1024 + tid;
    float a0 = acc0[t] + b0, a1 = acc1[t] + b1, a2 = acc2[t] + b2, a3 = acc3[t] + b3;
    dtout[o]       = (a0 > 20.f) ? a0 : logf(1.f + expf(a0));
    dtout[o + 256] = (a1 > 20.f) ? a1 : logf(1.f + expf(a1));
    dtout[o + 512] = (a2 > 20.f) ? a2 : logf(1.f + expf(a2));
    dtout[o + 768] = (a3 > 20.f) ? a3 : logf(1.f + expf(a3));
  }
}

// ---------------- chunked selective scan, lane-owns-d ----------------
// U/H0 layout: [b][c][n][d]; SD: [b][c][d]; A2T_l: [n][d] (coalesced).
__global__ __launch_bounds__(256) void scan1(
    const float* __restrict__ dt, const float* __restrict__ xc,
    const float* __restrict__ dbc, const float* __restrict__ A2T_l,
    float* __restrict__ Ubuf, float* __restrict__ SD, int NCc, int TCc) {
  const int d = blockIdx.x * 256 + threadIdx.x;
  const int c = blockIdx.y;
  const int b = blockIdx.z;
  const int t0 = c * TCc;
  __shared__ __align__(16) float sB[64][16];
  for (int i = threadIdx.x; i < TCc * 16; i += 256) {
    int t = i >> 4, n = i & 15;
    sB[t][n] = dbc[((size_t)(b * 1024 + t0 + t)) * 64 + 32 + n];
  }
  float A2[16];
#pragma unroll
  for (int n = 0; n < 16; ++n) A2[n] = A2T_l[(size_t)n * 1024 + d];
  __syncthreads();
  float hc[16];
#pragma unroll
  for (int n = 0; n < 16; ++n) hc[n] = 0.f;
  float sumdt = 0.f;
  size_t tok = (size_t)b * 1024 + t0;
  for (int t = 0; t < TCc; ++t, ++tok) {
    float dtv = dt[tok * 1024 + d];
    float xcv = xc[tok * 1024 + d];
    float du = dtv * xcv;
    sumdt += dtv;
#pragma unroll
    for (int q = 0; q < 4; ++q) {
      float4 B4 = *(const float4*)(&sB[t][q * 4]);
      float e0 = exp2f(dtv * A2[q * 4 + 0]);
      float e1 = exp2f(dtv * A2[q * 4 + 1]);
      float e2 = exp2f(dtv * A2[q * 4 + 2]);
      float e3 = exp2f(dtv * A2[q * 4 + 3]);
      hc[q * 4 + 0] = e0 * hc[q * 4 + 0] + du * B4.x;
      hc[q * 4 + 1] = e1 * hc[q * 4 + 1] + du * B4.y;
      hc[q * 4 + 2] = e2 * hc[q * 4 + 2] + du * B4.z;
      hc[q * 4 + 3] = e3 * hc[q * 4 + 3] + du * B4.w;
    }
  }
  size_t ob = (((size_t)b * NCc + c) * 16) * 1024 + d;
#pragma unroll
  for (int n = 0; n < 16; ++n) Ubuf[ob + (size_t)n * 1024] = hc[n];
  SD[((size_t)b * NCc + c) * 1024 + d] = sumdt;
}

// prefix-scan chunk summaries -> H0[b][c][n][d]; E recomputed from SD + A2T
__global__ __launch_bounds__(256) void scan_mid(
    const float* __restrict__ Ubuf, const float* __restrict__ SD,
    const float* __restrict__ A2T_l, float* __restrict__ H0, int NCc) {
  int idx = blockIdx.x * 256 + threadIdx.x;   // b*16384 + n*1024 + d
  int b = idx >> 14;
  int nd = idx & 16383;
  int d = nd & 1023;
  const float A2 = A2T_l[nd];                  // [n][d] coalesced
  float h = 0.f;
  size_t o0 = ((size_t)b * NCc * 16) * 1024 + nd;
  const size_t cstr = (size_t)16 * 1024;
  size_t sd0 = ((size_t)b * NCc) * 1024 + d;
  for (int cc = 0; cc < NCc; ++cc) {
    size_t o = o0 + (size_t)cc * cstr;
    H0[o] = h;
    if (cc < NCc - 1) {
      float e = exp2f(A2 * SD[sd0 + (size_t)cc * 1024]);
      h = e * h + Ubuf[o];
    }
  }
}

__global__ __launch_bounds__(256) void scan2(
    const float* __restrict__ dt, const float* __restrict__ xc,
    const float* __restrict__ dbc, const u16* __restrict__ xz,
    const float* __restrict__ A2T_l, const float* __restrict__ Dp,
    const float* __restrict__ H0, u16* __restrict__ yg, int NCc, int TCc) {
  const int d = blockIdx.x * 256 + threadIdx.x;
  const int c = blockIdx.y;
  const int b = blockIdx.z;
  const int t0 = c * TCc;
  __shared__ __align__(16) float sB[64][16];
  __shared__ __align__(16) float sC[64][16];
  for (int i = threadIdx.x; i < TCc * 16; i += 256) {
    int t = i >> 4, n = i & 15;
    size_t o = ((size_t)(b * 1024 + t0 + t)) * 64 + 32;
    sB[t][n] = dbc[o + n];
    sC[t][n] = dbc[o + 16 + n];
  }
  float A2[16];
#pragma unroll
  for (int n = 0; n < 16; ++n) A2[n] = A2T_l[(size_t)n * 1024 + d];
  const float Dd = Dp[d];
  float hc[16];
  size_t ob = (((size_t)b * NCc + c) * 16) * 1024 + d;
#pragma unroll
  for (int n = 0; n < 16; ++n) hc[n] = H0[ob + (size_t)n * 1024];
  __syncthreads();
  size_t tok = (size_t)b * 1024 + t0;
  for (int t = 0; t < TCc; ++t, ++tok) {
    float dtv = dt[tok * 1024 + d];
    float xcv = xc[tok * 1024 + d];
    float du = dtv * xcv;
    float y0 = 0.f, y1 = 0.f, y2 = 0.f, y3 = 0.f;
#pragma unroll
    for (int q = 0; q < 4; ++q) {
      float4 B4 = *(const float4*)(&sB[t][q * 4]);
      float4 C4 = *(const float4*)(&sC[t][q * 4]);
      float e0 = exp2f(dtv * A2[q * 4 + 0]);
      float e1 = exp2f(dtv * A2[q * 4 + 1]);
      float e2 = exp2f(dtv * A2[q * 4 + 2]);
      float e3 = exp2f(dtv * A2[q * 4 + 3]);
      hc[q * 4 + 0] = e0 * hc[q * 4 + 0] + du * B4.x;
      hc[q * 4 + 1] = e1 * hc[q * 4 + 1] + du * B4.y;
      hc[q * 4 + 2] = e2 * hc[q * 4 + 2] + du * B4.z;
      hc[q * 4 + 3] = e3 * hc[q * 4 + 3] + du * B4.w;
      y0 += hc[q * 4 + 0] * C4.x;
      y1 += hc[q * 4 + 1] * C4.y;
      y2 += hc[q * 4 + 2] * C4.z;
      y3 += hc[q * 4 + 3] * C4.w;
    }
    float y = (y0 + y1) + (y2 + y3);
    float z = b2f(xz[tok * 2048 + 1024 + d]);
    float g = z / (1.f + expf(-z));
    yg[tok * 1024 + d] = f2b((y + Dd * xcv) * g);
  }
}

// ---------------- reward head: out = t1sr[:,256:] @ ro_w2^T + b --------------
__global__ __launch_bounds__(256) void reward_head_kernel(
    const u16* __restrict__ t1sr, const float* __restrict__ w2,
    const float* __restrict__ b2, float* __restrict__ outr) {
  int tok = blockIdx.x * 4 + (threadIdx.x >> 6);
  int lane = threadIdx.x & 63;
  float s = 0.f;
#pragma unroll
  for (int j = 0; j < 256; j += 64)
    s += b2f(t1sr[(size_t)tok * 512 + 256 + j + lane]) * w2[j + lane];
#pragma unroll
  for (int o = 32; o; o >>= 1) s += __shfl_xor(s, o);
  if (lane == 0) outr[tok] = s + b2[0];
}

extern "C" void kernel_launch(void* const* d_in, const int* in_sizes, int n_in,
                              void* d_out, int out_size, void* d_ws, size_t ws_size,
                              hipStream_t stream) {
  const float* x    = (const float*)d_in[0];
  const float* rtg  = (const float*)d_in[1];
  const float* Wse  = (const float*)d_in[2];
  const float* bse  = (const float*)d_in[3];
  const float* Wre  = (const float*)d_in[4];
  const float* bre  = (const float*)d_in[5];
  const float* lnw  = (const float*)d_in[6];
  const float* lnb  = (const float*)d_in[7];
  const float* ipw  = (const float*)d_in[8];
  const float* cw   = (const float*)d_in[9];
  const float* cb   = (const float*)d_in[10];
  const float* xpw  = (const float*)d_in[11];
  const float* dpw  = (const float*)d_in[12];
  const float* dpb  = (const float*)d_in[13];
  const float* Alog = (const float*)d_in[14];
  const float* Dp   = (const float*)d_in[15];
  const float* opw  = (const float*)d_in[16];
  const float* nw   = (const float*)d_in[17];
  const float* nfw  = (const float*)d_in[18];
  const float* sow1 = (const float*)d_in[19];
  const float* sob1 = (const float*)d_in[20];
  const float* sow2 = (const float*)d_in[21];
  const float* sob2 = (const float*)d_in[22];
  const float* row1 = (const float*)d_in[23];
  const float* rob1 = (const float*)d_in[24];
  const float* row2 = (const float*)d_in[25];
  const float* rob2 = (const float*)d_in[26];
  (void)in_sizes; (void)n_in; (void)out_size;

  char* wsp = (char*)d_ws;
  size_t off = 0;
  auto alloc = [&](size_t bytes) -> void* {
    off = (off + 255) & ~(size_t)255;
    void* p = wsp + off;
    off += bytes;
    return p;
  };
  const int TOK = 4096;
  float* h     = (float*)alloc((size_t)TOK * 512 * 4);
  float* resid = (float*)alloc((size_t)TOK * 512 * 4);
  u16* hn      = (u16*)alloc((size_t)TOK * 512 * 2);
  u16* xzb     = (u16*)alloc((size_t)TOK * 2048 * 2);
  float* xcf   = (float*)alloc((size_t)TOK * 1024 * 4);
  u16* xcb     = (u16*)alloc((size_t)TOK * 1024 * 2);   // conv bf16; scan2 overwrites w/ gated y
  float* dbcP  = (float*)alloc((size_t)8 * TOK * 64 * 4);  // x_proj K-split x8 partials
  float* dbc   = (float*)alloc((size_t)TOK * 64 * 4);
  float* dtf   = (float*)alloc((size_t)TOK * 1024 * 4);
  float* PEt   = (float*)alloc((size_t)1024 * 512 * 4);
  float* dpwT  = (float*)alloc((size_t)4 * 32 * 1024 * 4);
  float* cwT   = (float*)alloc((size_t)4 * 4 * 1024 * 4);
  float* A2T   = (float*)alloc((size_t)4 * 16 * 1024 * 4);
  u16* ipwb    = (u16*)alloc((size_t)4 * 2048 * 512 * 2);
  u16* xpwb    = (u16*)alloc((size_t)4 * 64 * 1024 * 2);
  u16* opwb    = (u16*)alloc((size_t)4 * 512 * 1024 * 2);
  u16* sow1b   = (u16*)alloc((size_t)256 * 512 * 2);    // sow1b/row1b adjacent (merged head)
  u16* row1b   = (u16*)alloc((size_t)256 * 512 * 2);
  u16* sow2b   = (u16*)alloc((size_t)128 * 256 * 2);

  // pick NC by available workspace (deterministic in ws_size -> graph-safe)
  // need: U = 4*NC*16*1024*4, H0 same, SD = 4*NC*1024*4
  size_t base_off = (off + 255) & ~(size_t)255;
  auto scan_bytes = [](int nc) {
    return (size_t)2 * 4 * nc * 16 * 1024 * 4 + (size_t)4 * nc * 1024 * 4 + 1024;
  };
  int NCc = 16;
  if (ws_size >= base_off + scan_bytes(64)) NCc = 64;
  else if (ws_size >= base_off + scan_bytes(32)) NCc = 32;
  int TCc = 1024 / NCc;
  // U (scan chunk state) aliased with t1sr (head temp, post-layer only)
  float* Ubuf  = (float*)alloc((size_t)4096 * NCc * 16 * 4);
  float* H0    = (float*)alloc((size_t)4096 * NCc * 16 * 4);
  float* SD    = (float*)alloc((size_t)4 * NCc * 1024 * 4);
  u16* t1sr    = (u16*)Ubuf;                             // [4096][512] bf16 = 4MB

  setup_kernel<<<29632, 256, 0, stream>>>(ipw, ipwb, xpw, xpwb, opw, opwb,
                                          sow1, sow1b, sow2, sow2b, row1, row1b,
                                          PEt, dpw, dpwT, cw, cwT, Alog, A2T);
  embed_ln2<<<256, 256, 0, stream>>>(x, rtg, Wse, bse, Wre, bre, lnw, lnb, PEt, h);

  for (int i = 0; i < 4; ++i) {
    const float* A2Tl = A2T + (size_t)i * 16 * 1024;
    resid_rms_kernel<<<TOK, 256, 0, stream>>>(h, resid, nw + i * 512, hn, i == 0);
    gemm_bt<128, 128, 2, 2, 1><<<dim3(32, 16, 1), 256, 0, stream>>>(
        hn, ipwb + (size_t)i * 2048 * 512, nullptr, xzb, nullptr, nullptr,
        4096, 2048, 512, 512);
    conv_silu_f<<<2048, 256, 0, stream>>>(
        xzb, cwT + (size_t)i * 4096, cb + i * 1024, xcf, xcb);
    gemm_bt<64, 64, 2, 2, 0><<<dim3(64, 1, 8), 256, 0, stream>>>(
        xcb, xpwb + (size_t)i * 64 * 1024, dbcP, nullptr, nullptr, nullptr,
        4096, 64, 1024, 1024);
    dt_kernel2<<<TOK / 16, 256, 0, stream>>>(dbcP, dpwT + (size_t)i * 32 * 1024,
                                             dpb + i * 1024, dtf, dbc);
    scan1<<<dim3(4, NCc - 1, 4), 256, 0, stream>>>(
        dtf, xcf, dbc, A2Tl, Ubuf, SD, NCc, TCc);
    scan_mid<<<256, 256, 0, stream>>>(Ubuf, SD, A2Tl, H0, NCc);
    scan2<<<dim3(4, NCc, 4), 256, 0, stream>>>(
        dtf, xcf, dbc, xzb, A2Tl, Dp + i * 1024, H0, xcb, NCc, TCc);
    gemm_bt<64, 64, 2, 2, 0><<<dim3(64, 8, 1), 256, 0, stream>>>(
        xcb, opwb + (size_t)i * 512 * 1024, h, nullptr, nullptr, nullptr,
        4096, 512, 1024, 1024);
  }

  resid_rms_kernel<<<TOK, 256, 0, stream>>>(h, resid, nfw, hn, 0);
  gemm_bt<64, 64, 2, 2, 4><<<dim3(64, 8, 1), 256, 0, stream>>>(
      hn, sow1b, nullptr, t1sr, sob1, rob1, 4096, 512, 512, 512);
  gemm_bt<64, 64, 2, 2, 3><<<dim3(64, 2, 1), 256, 0, stream>>>(
      t1sr, sow2b, (float*)d_out, nullptr, sob2, nullptr, 4096, 128, 256, 512);
  reward_head_kernel<<<TOK / 4, 256, 0, stream>>>(
      t1sr, row2, rob2, (float*)d_out + (size_t)TOK * 128);
}

// Round 14
// 646.491 us; speedup vs baseline: 1.0415x; 1.0042x over previous
//
#include <hip/hip_runtime.h>
#include <stdint.h>

typedef unsigned short u16;
typedef __attribute__((ext_vector_type(8))) short bf16x8;
typedef __attribute__((ext_vector_type(8))) u16 u16x8;
typedef __attribute__((ext_vector_type(4))) float f32x4;

static __device__ __forceinline__ u16 f2b(float f) {
  uint32_t u = __builtin_bit_cast(uint32_t, f);
  u += 0x7fffu + ((u >> 16) & 1u);
  return (u16)(u >> 16);
}
static __device__ __forceinline__ float b2f(u16 h) {
  uint32_t u = ((uint32_t)h) << 16;
  return __builtin_bit_cast(float, u);
}

#define GLDS16(gsrc, ldst)                                                        \
  __builtin_amdgcn_global_load_lds(                                               \
      (const __attribute__((address_space(1))) void*)(gsrc),                      \
      (__attribute__((address_space(3))) void*)(ldst), 16, 0, 0)

// ---------------- all setup work in ONE kernel ----------------
// segments: 6 weight casts, PE table, dpw transpose, cw transpose, A2T table
__global__ __launch_bounds__(256) void setup_kernel(
    const float* __restrict__ ipw, u16* __restrict__ ipwb,
    const float* __restrict__ xpw, u16* __restrict__ xpwb,
    const float* __restrict__ opw, u16* __restrict__ opwb,
    const float* __restrict__ sow1, u16* __restrict__ sow1b,
    const float* __restrict__ sow2, u16* __restrict__ sow2b,
    const float* __restrict__ row1, u16* __restrict__ row1b,
    float* __restrict__ PEt,
    const float* __restrict__ dpw, float* __restrict__ dpwT,
    const float* __restrict__ cw, float* __restrict__ cwT,
    const float* __restrict__ Alog, float* __restrict__ A2T) {
  int i = blockIdx.x * 256 + threadIdx.x;
  if (i < 4194304) { ipwb[i] = f2b(ipw[i]); return; } i -= 4194304;
  if (i < 262144)  { xpwb[i] = f2b(xpw[i]); return; } i -= 262144;
  if (i < 2097152) { opwb[i] = f2b(opw[i]); return; } i -= 2097152;
  if (i < 131072)  { sow1b[i] = f2b(sow1[i]); return; } i -= 131072;
  if (i < 32768)   { sow2b[i] = f2b(sow2[i]); return; } i -= 32768;
  if (i < 131072)  { row1b[i] = f2b(row1[i]); return; } i -= 131072;
  if (i < 524288) {  // PE: i = l*512 + dd
    int dd = i & 511, l = i >> 9;
    const float cc = -9.210340371976184f / 512.f;
    float div = expf((float)(2 * (dd >> 1)) * cc);
    PEt[i] = (dd & 1) ? cosf((float)l * div) : sinf((float)l * div);
    return;
  } i -= 524288;
  if (i < 131072) {  // dpwT[l][j][dd] = dpw[l][dd][j]
    int l = i >> 15, r = i & 32767, j = r >> 10, dd = r & 1023;
    dpwT[i] = dpw[(size_t)l * 32768 + (size_t)dd * 32 + j];
    return;
  } i -= 131072;
  if (i < 16384) {   // cwT[l][k][dd] = cw[l][dd][k]
    int l = i >> 12, r = i & 4095, k = r >> 10, dd = r & 1023;
    cwT[i] = cw[(size_t)l * 4096 + (size_t)dd * 4 + k];
    return;
  } i -= 16384;
  if (i < 65536) {   // A2T[l][n][d] = -exp(Alog[l][d][n]) * log2(e)
    int l = i >> 14, r = i & 16383, n = r >> 10, d = r & 1023;
    A2T[i] = -expf(Alog[(size_t)l * 16384 + (size_t)d * 16 + n]) * 1.4426950408889634f;
  }
}

// ---------------- embedding + PE + LayerNorm (16 tokens/block) ----------------
__global__ __launch_bounds__(256) void embed_ln2(
    const float* __restrict__ x, const float* __restrict__ rtg,
    const float* __restrict__ Wse, const float* __restrict__ bse,
    const float* __restrict__ Wre, const float* __restrict__ bre,
    const float* __restrict__ lnw, const float* __restrict__ lnb,
    const float* __restrict__ PEt, float* __restrict__ h) {
  const int tid = threadIdx.x;
  const int tok0 = blockIdx.x * 16;
  const int l0 = tok0 & 1023;
  __shared__ float xs[16][128];
  __shared__ float rt[16];
  __shared__ float sw[16][2][4];
  for (int i = tid; i < 16 * 128; i += 256) ((float*)xs)[i] = x[(size_t)tok0 * 128 + i];
  if (tid < 16) rt[tid] = rtg[tok0 + tid];
  __syncthreads();
  const int d = tid;
  float acc[16];
#pragma unroll
  for (int tt = 0; tt < 16; ++tt) acc[tt] = 0.f;
  const float* wrow = Wse + (size_t)d * 128;
  for (int k0 = 0; k0 < 128; k0 += 8) {
    float4 wa = *(const float4*)(wrow + k0);
    float4 wb = *(const float4*)(wrow + k0 + 4);
#pragma unroll
    for (int tt = 0; tt < 16; ++tt) {
      const float* xr = &xs[tt][k0];
      acc[tt] += xr[0] * wa.x + xr[1] * wa.y + xr[2] * wa.z + xr[3] * wa.w +
                 xr[4] * wb.x + xr[5] * wb.y + xr[6] * wb.z + xr[7] * wb.w;
    }
  }
  const float seb = bse[d], reW = Wre[d], reB = bre[d];
  const int lane = tid & 63, wv = tid >> 6;
  float h1a[16];
#pragma unroll
  for (int tt = 0; tt < 16; ++tt) {
    float h0 = acc[tt] + seb + PEt[(size_t)(l0 + tt) * 512 + d];
    float h1 = reB + rt[tt] * reW + PEt[(size_t)(l0 + tt) * 512 + 256 + d];
    acc[tt] = h0;
    h1a[tt] = h1;
    float s = h0 + h1, q = h0 * h0 + h1 * h1;
#pragma unroll
    for (int o = 32; o; o >>= 1) { s += __shfl_xor(s, o); q += __shfl_xor(q, o); }
    if (lane == 0) { sw[tt][0][wv] = s; sw[tt][1][wv] = q; }
  }
  __syncthreads();
#pragma unroll
  for (int tt = 0; tt < 16; ++tt) {
    float S = sw[tt][0][0] + sw[tt][0][1] + sw[tt][0][2] + sw[tt][0][3];
    float Q = sw[tt][1][0] + sw[tt][1][1] + sw[tt][1][2] + sw[tt][1][3];
    float mean = S * (1.f / 512.f);
    float var = Q * (1.f / 512.f) - mean * mean;
    float rstd = rsqrtf(var + 1e-5f);
    size_t base = (size_t)(tok0 + tt) * 512;
    h[base + d]       = (acc[tt] - mean) * rstd * lnw[d] + lnb[d];
    h[base + 256 + d] = (h1a[tt] - mean) * rstd * lnw[256 + d] + lnb[256 + d];
  }
}

// ---------------- residual add + RMSNorm -> bf16 ----------------
__global__ __launch_bounds__(256) void resid_rms_kernel(
    const float* __restrict__ hin, float* __restrict__ residual,
    const float* __restrict__ w, u16* __restrict__ outb, int first) {
  const int tok = blockIdx.x;
  const int t = threadIdx.x;
  __shared__ float rq[4];
  size_t base = (size_t)tok * 512;
  float v0 = hin[base + t], v1 = hin[base + t + 256];
  if (!first) { v0 += residual[base + t]; v1 += residual[base + t + 256]; }
  residual[base + t] = v0;
  residual[base + t + 256] = v1;
  float q = v0 * v0 + v1 * v1;
#pragma unroll
  for (int o = 32; o; o >>= 1) q += __shfl_xor(q, o);
  if ((t & 63) == 0) rq[t >> 6] = q;
  __syncthreads();
  float Q = rq[0] + rq[1] + rq[2] + rq[3];
  float scale = rsqrtf(Q * (1.f / 512.f) + 1e-5f);
  outb[base + t]       = f2b(v0 * scale * w[t]);
  outb[base + t + 256] = f2b(v1 * scale * w[t + 256]);
}

// ---------------- MFMA GEMM: C[M,N] = A[M,K] * Bw[N,K]^T ----------------
// As = A row stride. EPI: 0=f32, 1=bf16, 2=bias+relu->bf16, 3=bias->f32,
// 4=dual-bias+relu->bf16 (bias[col<256], bias2[col-256])
template <int BM, int BN, int WM, int WN, int EPI>
__global__ __launch_bounds__(256) void gemm_bt(
    const u16* __restrict__ A, const u16* __restrict__ Bw,
    float* __restrict__ Cf, u16* __restrict__ Cb,
    const float* __restrict__ bias, const float* __restrict__ bias2,
    int M, int N, int K, int As) {
  constexpr int MF = BM / (WM * 16);
  constexpr int NF = BN / (WN * 16);
  constexpr int NCA = (BM * 4) / 256;
  constexpr int NCB = (BN * 4) / 256;
  __shared__ __align__(16) u16 lA[BM * 32];
  __shared__ __align__(16) u16 lB[BN * 32];
  const int tid = threadIdx.x;
  const int lane = tid & 63;
  const int wv = tid >> 6;
  const int wr = wv / WN, wc = wv % WN;
  const int m0 = blockIdx.x * BM, n0 = blockIdx.y * BN;
  const int kchunk = K / gridDim.z;
  const int kb = blockIdx.z * kchunk;

  f32x4 acc[MF][NF];
#pragma unroll
  for (int i = 0; i < MF; ++i)
#pragma unroll
    for (int j = 0; j < NF; ++j) acc[i][j] = (f32x4){0.f, 0.f, 0.f, 0.f};

  const int srow = tid >> 2, sck = tid & 3;
  const u16* Ag = A + (size_t)(m0 + srow) * As + sck * 8 + kb;
  const u16* Bg = Bw + (size_t)(n0 + srow) * K + sck * 8 + kb;

  for (int k0 = 0; k0 < kchunk; k0 += 32) {
#pragma unroll
    for (int it = 0; it < NCA; ++it)
      GLDS16(Ag + (size_t)it * 64 * As + k0, &lA[(it * 256 + tid) * 8]);
#pragma unroll
    for (int it = 0; it < NCB; ++it)
      GLDS16(Bg + (size_t)it * 64 * K + k0, &lB[(it * 256 + tid) * 8]);
    __syncthreads();
    bf16x8 af[MF], bfr[NF];
    const int koff = (lane >> 4) * 8;
#pragma unroll
    for (int mi = 0; mi < MF; ++mi) {
      int r = wr * (MF * 16) + mi * 16 + (lane & 15);
      af[mi] = *(const bf16x8*)(&lA[r * 32 + koff]);
    }
#pragma unroll
    for (int ni = 0; ni < NF; ++ni) {
      int r = wc * (NF * 16) + ni * 16 + (lane & 15);
      bfr[ni] = *(const bf16x8*)(&lB[r * 32 + koff]);
    }
#pragma unroll
    for (int mi = 0; mi < MF; ++mi)
#pragma unroll
      for (int ni = 0; ni < NF; ++ni)
        acc[mi][ni] = __builtin_amdgcn_mfma_f32_16x16x32_bf16(af[mi], bfr[ni], acc[mi][ni], 0, 0, 0);
    __syncthreads();
  }

  float* co = Cf + (size_t)blockIdx.z * (size_t)M * N;
  const int rbase = (lane >> 4) * 4;
  const int cbase = lane & 15;
#pragma unroll
  for (int mi = 0; mi < MF; ++mi) {
#pragma unroll
    for (int ni = 0; ni < NF; ++ni) {
      int row = m0 + wr * (MF * 16) + mi * 16 + rbase;
      int col = n0 + wc * (NF * 16) + ni * 16 + cbase;
      float bv = 0.f;
      if (EPI == 2 || EPI == 3) bv = bias[col];
      if (EPI == 4) bv = (col < 256) ? bias[col] : bias2[col - 256];
#pragma unroll
      for (int r = 0; r < 4; ++r) {
        float v = acc[mi][ni][r] + bv;
        if (EPI == 2 || EPI == 4) v = fmaxf(v, 0.f);
        size_t idx = (size_t)(row + r) * N + col;
        if (EPI == 1 || EPI == 2 || EPI == 4) Cb[idx] = f2b(v);
        else co[idx] = v;
      }
    }
  }
}

// ------- causal depthwise conv(K=4) + silu, 8 d/thread, bf16 out -------------
__global__ __launch_bounds__(256) void conv_silu3(
    const u16* __restrict__ xz, const float* __restrict__ cwT,
    const float* __restrict__ cb, u16* __restrict__ xcb) {
  int gid = blockIdx.x * 256 + threadIdx.x;     // over 4*1024*128 groups
  int d0 = (gid & 127) * 8;
  int token = gid >> 7;
  int t = token & 1023;
  const u16* xx = xz + (size_t)(token - t) * 2048 + d0;
  float s[8];
  {
    float4 cba = *(const float4*)(cb + d0);
    float4 cbb = *(const float4*)(cb + d0 + 4);
    s[0] = cba.x; s[1] = cba.y; s[2] = cba.z; s[3] = cba.w;
    s[4] = cbb.x; s[5] = cbb.y; s[6] = cbb.z; s[7] = cbb.w;
  }
#pragma unroll
  for (int k = 0; k < 4; ++k) {
    int tt = t - 3 + k;
    if (tt >= 0) {
      u16x8 v = *(const u16x8*)(xx + (size_t)tt * 2048);
      float4 wA = *(const float4*)(cwT + (size_t)k * 1024 + d0);
      float4 wB = *(const float4*)(cwT + (size_t)k * 1024 + d0 + 4);
      s[0] += wA.x * b2f(v[0]); s[1] += wA.y * b2f(v[1]);
      s[2] += wA.z * b2f(v[2]); s[3] += wA.w * b2f(v[3]);
      s[4] += wB.x * b2f(v[4]); s[5] += wB.y * b2f(v[5]);
      s[6] += wB.z * b2f(v[6]); s[7] += wB.w * b2f(v[7]);
    }
  }
  u16x8 o;
#pragma unroll
  for (int j = 0; j < 8; ++j) {
    float sl = s[j] / (1.f + expf(-s[j]));
    o[j] = f2b(sl);
  }
  *(u16x8*)(xcb + (size_t)token * 1024 + d0) = o;
}

// ---- reduce x_proj partials (8-way K-split) + dt = softplus(...) -> bf16 ----
__global__ __launch_bounds__(256) void dt_kernel2(
    const float* __restrict__ P, const float* __restrict__ dpwT,
    const float* __restrict__ dpb, u16* __restrict__ dtout,
    float* __restrict__ dbcr) {
  const int tid = threadIdx.x;
  const int tok0 = blockIdx.x * 16;
  __shared__ float sm[16][64];
  const size_t str = (size_t)4096 * 64;
  for (int i = tid; i < 16 * 64; i += 256) {
    size_t o = (size_t)tok0 * 64 + i;
    float v = 0.f;
#pragma unroll
    for (int p = 0; p < 8; ++p) v += P[(size_t)p * str + o];
    ((float*)sm)[i] = v;
    dbcr[o] = v;
  }
  __syncthreads();
  float acc0[16], acc1[16], acc2[16], acc3[16];
#pragma unroll
  for (int t = 0; t < 16; ++t) { acc0[t] = 0.f; acc1[t] = 0.f; acc2[t] = 0.f; acc3[t] = 0.f; }
#pragma unroll 4
  for (int j = 0; j < 32; ++j) {
    float w0 = dpwT[(size_t)j * 1024 + tid];
    float w1 = dpwT[(size_t)j * 1024 + 256 + tid];
    float w2 = dpwT[(size_t)j * 1024 + 512 + tid];
    float w3 = dpwT[(size_t)j * 1024 + 768 + tid];
#pragma unroll
    for (int t = 0; t < 16; ++t) {
      float sv = sm[t][j];
      acc0[t] += sv * w0;
      acc1[t] += sv * w1;
      acc2[t] += sv * w2;
      acc3[t] += sv * w3;
    }
  }
  const float b0 = dpb[tid], b1 = dpb[256 + tid], b2 = dpb[512 + tid], b3 = dpb[768 + tid];
#pragma unroll
  for (int t = 0; t < 16; ++t) {
    size_t o = (size_t)(tok0 + t) * 1024 + tid;
    float a0 = acc0[t] + b0, a1 = acc1[t] + b1, a2 = acc2[t] + b2, a3 = acc3[t] + b3;
    dtout[o]       = f2b((a0 > 20.f) ? a0 : logf(1.f + expf(a0)));
    dtout[o + 256] = f2b((a1 > 20.f) ? a1 : logf(1.f + expf(a1)));
    dtout[o + 512] = f2b((a2 > 20.f) ? a2 : logf(1.f + expf(a2)));
    dtout[o + 768] = f2b((a3 > 20.f) ? a3 : logf(1.f + expf(a3)));
  }
}

// ---------------- chunked selective scan, lane-owns-d, bf16 inputs ----------
// U/H0 layout: [b][c][n][d]; SD: [b][c][d]; A2T_l: [n][d] (coalesced).
__global__ __launch_bounds__(256) void scan1(
    const u16* __restrict__ dt, const u16* __restrict__ xc,
    const float* __restrict__ dbc, const float* __restrict__ A2T_l,
    float* __restrict__ Ubuf, float* __restrict__ SD, int NCc, int TCc) {
  const int d = blockIdx.x * 256 + threadIdx.x;
  const int c = blockIdx.y;
  const int b = blockIdx.z;
  const int t0 = c * TCc;
  __shared__ __align__(16) float sB[64][16];
  for (int i = threadIdx.x; i < TCc * 16; i += 256) {
    int t = i >> 4, n = i & 15;
    sB[t][n] = dbc[((size_t)(b * 1024 + t0 + t)) * 64 + 32 + n];
  }
  float A2[16];
#pragma unroll
  for (int n = 0; n < 16; ++n) A2[n] = A2T_l[(size_t)n * 1024 + d];
  __syncthreads();
  float hc[16];
#pragma unroll
  for (int n = 0; n < 16; ++n) hc[n] = 0.f;
  float sumdt = 0.f;
  size_t tok = (size_t)b * 1024 + t0;
  for (int t = 0; t < TCc; ++t, ++tok) {
    float dtv = b2f(dt[tok * 1024 + d]);
    float xcv = b2f(xc[tok * 1024 + d]);
    float du = dtv * xcv;
    sumdt += dtv;
#pragma unroll
    for (int q = 0; q < 4; ++q) {
      float4 B4 = *(const float4*)(&sB[t][q * 4]);
      float e0 = exp2f(dtv * A2[q * 4 + 0]);
      float e1 = exp2f(dtv * A2[q * 4 + 1]);
      float e2 = exp2f(dtv * A2[q * 4 + 2]);
      float e3 = exp2f(dtv * A2[q * 4 + 3]);
      hc[q * 4 + 0] = e0 * hc[q * 4 + 0] + du * B4.x;
      hc[q * 4 + 1] = e1 * hc[q * 4 + 1] + du * B4.y;
      hc[q * 4 + 2] = e2 * hc[q * 4 + 2] + du * B4.z;
      hc[q * 4 + 3] = e3 * hc[q * 4 + 3] + du * B4.w;
    }
  }
  size_t ob = (((size_t)b * NCc + c) * 16) * 1024 + d;
#pragma unroll
  for (int n = 0; n < 16; ++n) Ubuf[ob + (size_t)n * 1024] = hc[n];
  SD[((size_t)b * NCc + c) * 1024 + d] = sumdt;
}

// prefix-scan chunk summaries -> H0[b][c][n][d]; E recomputed from SD + A2T
__global__ __launch_bounds__(256) void scan_mid(
    const float* __restrict__ Ubuf, const float* __restrict__ SD,
    const float* __restrict__ A2T_l, float* __restrict__ H0, int NCc) {
  int idx = blockIdx.x * 256 + threadIdx.x;   // b*16384 + n*1024 + d
  int b = idx >> 14;
  int nd = idx & 16383;
  int d = nd & 1023;
  const float A2 = A2T_l[nd];                  // [n][d] coalesced
  float h = 0.f;
  size_t o0 = ((size_t)b * NCc * 16) * 1024 + nd;
  const size_t cstr = (size_t)16 * 1024;
  size_t sd0 = ((size_t)b * NCc) * 1024 + d;
  for (int cc = 0; cc < NCc; ++cc) {
    size_t o = o0 + (size_t)cc * cstr;
    H0[o] = h;
    if (cc < NCc - 1) {
      float e = exp2f(A2 * SD[sd0 + (size_t)cc * 1024]);
      h = e * h + Ubuf[o];
    }
  }
}

__global__ __launch_bounds__(256) void scan2(
    const u16* __restrict__ dt, const u16* __restrict__ xc,
    const float* __restrict__ dbc, const u16* __restrict__ xz,
    const float* __restrict__ A2T_l, const float* __restrict__ Dp,
    const float* __restrict__ H0, u16* __restrict__ yg, int NCc, int TCc) {
  const int d = blockIdx.x * 256 + threadIdx.x;
  const int c = blockIdx.y;
  const int b = blockIdx.z;
  const int t0 = c * TCc;
  __shared__ __align__(16) float sB[64][16];
  __shared__ __align__(16) float sC[64][16];
  for (int i = threadIdx.x; i < TCc * 16; i += 256) {
    int t = i >> 4, n = i & 15;
    size_t o = ((size_t)(b * 1024 + t0 + t)) * 64 + 32;
    sB[t][n] = dbc[o + n];
    sC[t][n] = dbc[o + 16 + n];
  }
  float A2[16];
#pragma unroll
  for (int n = 0; n < 16; ++n) A2[n] = A2T_l[(size_t)n * 1024 + d];
  const float Dd = Dp[d];
  float hc[16];
  size_t ob = (((size_t)b * NCc + c) * 16) * 1024 + d;
#pragma unroll
  for (int n = 0; n < 16; ++n) hc[n] = H0[ob + (size_t)n * 1024];
  __syncthreads();
  size_t tok = (size_t)b * 1024 + t0;
  for (int t = 0; t < TCc; ++t, ++tok) {
    float dtv = b2f(dt[tok * 1024 + d]);
    float xcv = b2f(xc[tok * 1024 + d]);
    float du = dtv * xcv;
    float y0 = 0.f, y1 = 0.f, y2 = 0.f, y3 = 0.f;
#pragma unroll
    for (int q = 0; q < 4; ++q) {
      float4 B4 = *(const float4*)(&sB[t][q * 4]);
      float4 C4 = *(const float4*)(&sC[t][q * 4]);
      float e0 = exp2f(dtv * A2[q * 4 + 0]);
      float e1 = exp2f(dtv * A2[q * 4 + 1]);
      float e2 = exp2f(dtv * A2[q * 4 + 2]);
      float e3 = exp2f(dtv * A2[q * 4 + 3]);
      hc[q * 4 + 0] = e0 * hc[q * 4 + 0] + du * B4.x;
      hc[q * 4 + 1] = e1 * hc[q * 4 + 1] + du * B4.y;
      hc[q * 4 + 2] = e2 * hc[q * 4 + 2] + du * B4.z;
      hc[q * 4 + 3] = e3 * hc[q * 4 + 3] + du * B4.w;
      y0 += hc[q * 4 + 0] * C4.x;
      y1 += hc[q * 4 + 1] * C4.y;
      y2 += hc[q * 4 + 2] * C4.z;
      y3 += hc[q * 4 + 3] * C4.w;
    }
    float y = (y0 + y1) + (y2 + y3);
    float z = b2f(xz[tok * 2048 + 1024 + d]);
    float g = z / (1.f + expf(-z));
    yg[tok * 1024 + d] = f2b((y + Dd * xcv) * g);
  }
}

// ---------------- reward head: out = t1sr[:,256:] @ ro_w2^T + b --------------
__global__ __launch_bounds__(256) void reward_head_kernel(
    const u16* __restrict__ t1sr, const float* __restrict__ w2,
    const float* __restrict__ b2, float* __restrict__ outr) {
  int tok = blockIdx.x * 4 + (threadIdx.x >> 6);
  int lane = threadIdx.x & 63;
  float s = 0.f;
#pragma unroll
  for (int j = 0; j < 256; j += 64)
    s += b2f(t1sr[(size_t)tok * 512 + 256 + j + lane]) * w2[j + lane];
#pragma unroll
  for (int o = 32; o; o >>= 1) s += __shfl_xor(s, o);
  if (lane == 0) outr[tok] = s + b2[0];
}

extern "C" void kernel_launch(void* const* d_in, const int* in_sizes, int n_in,
                              void* d_out, int out_size, void* d_ws, size_t ws_size,
                              hipStream_t stream) {
  const float* x    = (const float*)d_in[0];
  const float* rtg  = (const float*)d_in[1];
  const float* Wse  = (const float*)d_in[2];
  const float* bse  = (const float*)d_in[3];
  const float* Wre  = (const float*)d_in[4];
  const float* bre  = (const float*)d_in[5];
  const float* lnw  = (const float*)d_in[6];
  const float* lnb  = (const float*)d_in[7];
  const float* ipw  = (const float*)d_in[8];
  const float* cw   = (const float*)d_in[9];
  const float* cb   = (const float*)d_in[10];
  const float* xpw  = (const float*)d_in[11];
  const float* dpw  = (const float*)d_in[12];
  const float* dpb  = (const float*)d_in[13];
  const float* Alog = (const float*)d_in[14];
  const float* Dp   = (const float*)d_in[15];
  const float* opw  = (const float*)d_in[16];
  const float* nw   = (const float*)d_in[17];
  const float* nfw  = (const float*)d_in[18];
  const float* sow1 = (const float*)d_in[19];
  const float* sob1 = (const float*)d_in[20];
  const float* sow2 = (const float*)d_in[21];
  const float* sob2 = (const float*)d_in[22];
  const float* row1 = (const float*)d_in[23];
  const float* rob1 = (const float*)d_in[24];
  const float* row2 = (const float*)d_in[25];
  const float* rob2 = (const float*)d_in[26];
  (void)in_sizes; (void)n_in; (void)out_size;

  char* wsp = (char*)d_ws;
  size_t off = 0;
  auto alloc = [&](size_t bytes) -> void* {
    off = (off + 255) & ~(size_t)255;
    void* p = wsp + off;
    off += bytes;
    return p;
  };
  const int TOK = 4096;
  float* h     = (float*)alloc((size_t)TOK * 512 * 4);
  float* resid = (float*)alloc((size_t)TOK * 512 * 4);
  u16* hn      = (u16*)alloc((size_t)TOK * 512 * 2);
  u16* xzb     = (u16*)alloc((size_t)TOK * 2048 * 2);
  u16* xcb     = (u16*)alloc((size_t)TOK * 1024 * 2);   // conv bf16; scan2 overwrites w/ gated y
  float* dbcP  = (float*)alloc((size_t)8 * TOK * 64 * 4);  // x_proj K-split x8 partials
  float* dbc   = (float*)alloc((size_t)TOK * 64 * 4);
  u16* dtb     = (u16*)alloc((size_t)TOK * 1024 * 2);
  float* PEt   = (float*)alloc((size_t)1024 * 512 * 4);
  float* dpwT  = (float*)alloc((size_t)4 * 32 * 1024 * 4);
  float* cwT   = (float*)alloc((size_t)4 * 4 * 1024 * 4);
  float* A2T   = (float*)alloc((size_t)4 * 16 * 1024 * 4);
  u16* ipwb    = (u16*)alloc((size_t)4 * 2048 * 512 * 2);
  u16* xpwb    = (u16*)alloc((size_t)4 * 64 * 1024 * 2);
  u16* opwb    = (u16*)alloc((size_t)4 * 512 * 1024 * 2);
  u16* sow1b   = (u16*)alloc((size_t)256 * 512 * 2);    // sow1b/row1b adjacent (merged head)
  u16* row1b   = (u16*)alloc((size_t)256 * 512 * 2);
  u16* sow2b   = (u16*)alloc((size_t)128 * 256 * 2);

  // pick NC by available workspace (deterministic in ws_size -> graph-safe)
  // need: U = 4*NC*16*1024*4, H0 same, SD = 4*NC*1024*4
  size_t base_off = (off + 255) & ~(size_t)255;
  auto scan_bytes = [](int nc) {
    return (size_t)2 * 4 * nc * 16 * 1024 * 4 + (size_t)4 * nc * 1024 * 4 + 1024;
  };
  int NCc = 16;
  if (ws_size >= base_off + scan_bytes(64)) NCc = 64;
  else if (ws_size >= base_off + scan_bytes(32)) NCc = 32;
  int TCc = 1024 / NCc;
  // U (scan chunk state) aliased with t1sr (head temp, post-layer only)
  float* Ubuf  = (float*)alloc((size_t)4096 * NCc * 16 * 4);
  float* H0    = (float*)alloc((size_t)4096 * NCc * 16 * 4);
  float* SD    = (float*)alloc((size_t)4 * NCc * 1024 * 4);
  u16* t1sr    = (u16*)Ubuf;                             // [4096][512] bf16 = 4MB

  setup_kernel<<<29632, 256, 0, stream>>>(ipw, ipwb, xpw, xpwb, opw, opwb,
                                          sow1, sow1b, sow2, sow2b, row1, row1b,
                                          PEt, dpw, dpwT, cw, cwT, Alog, A2T);
  embed_ln2<<<256, 256, 0, stream>>>(x, rtg, Wse, bse, Wre, bre, lnw, lnb, PEt, h);

  for (int i = 0; i < 4; ++i) {
    const float* A2Tl = A2T + (size_t)i * 16 * 1024;
    resid_rms_kernel<<<TOK, 256, 0, stream>>>(h, resid, nw + i * 512, hn, i == 0);
    gemm_bt<128, 128, 2, 2, 1><<<dim3(32, 16, 1), 256, 0, stream>>>(
        hn, ipwb + (size_t)i * 2048 * 512, nullptr, xzb, nullptr, nullptr,
        4096, 2048, 512, 512);
    conv_silu3<<<2048, 256, 0, stream>>>(
        xzb, cwT + (size_t)i * 4096, cb + i * 1024, xcb);
    gemm_bt<64, 64, 2, 2, 0><<<dim3(64, 1, 8), 256, 0, stream>>>(
        xcb, xpwb + (size_t)i * 64 * 1024, dbcP, nullptr, nullptr, nullptr,
        4096, 64, 1024, 1024);
    dt_kernel2<<<TOK / 16, 256, 0, stream>>>(dbcP, dpwT + (size_t)i * 32 * 1024,
                                             dpb + i * 1024, dtb, dbc);
    scan1<<<dim3(4, NCc - 1, 4), 256, 0, stream>>>(
        dtb, xcb, dbc, A2Tl, Ubuf, SD, NCc, TCc);
    scan_mid<<<256, 256, 0, stream>>>(Ubuf, SD, A2Tl, H0, NCc);
    scan2<<<dim3(4, NCc, 4), 256, 0, stream>>>(
        dtb, xcb, dbc, xzb, A2Tl, Dp + i * 1024, H0, xcb, NCc, TCc);
    gemm_bt<64, 64, 2, 2, 0><<<dim3(64, 8, 1), 256, 0, stream>>>(
        xcb, opwb + (size_t)i * 512 * 1024, h, nullptr, nullptr, nullptr,
        4096, 512, 1024, 1024);
  }

  resid_rms_kernel<<<TOK, 256, 0, stream>>>(h, resid, nfw, hn, 0);
  gemm_bt<64, 64, 2, 2, 4><<<dim3(64, 8, 1), 256, 0, stream>>>(
      hn, sow1b, nullptr, t1sr, sob1, rob1, 4096, 512, 512, 512);
  gemm_bt<64, 64, 2, 2, 3><<<dim3(64, 2, 1), 256, 0, stream>>>(
      t1sr, sow2b, (float*)d_out, nullptr, sob2, nullptr, 4096, 128, 256, 512);
  reward_head_kernel<<<TOK / 4, 256, 0, stream>>>(
      t1sr, row2, rob2, (float*)d_out + (size_t)TOK * 128);
}